// Round 3
// baseline (182.937 us; speedup 1.0000x reference)
//
#include <hip/hip_runtime.h>
#include <hip/hip_bf16.h>
#include <stdint.h>

// Shapes (fixed by the problem)
#define B_ROWS 16384
#define VDIM   16
#define SDIM   64
#define HDIM   512
#define KDIM   1024   // V*S
#define KP     1056   // KDIM + 16 bias cols + 16 zero pad (multiple of 32)

using bf16x8 = __attribute__((ext_vector_type(8))) __bf16;
using u16x8  = __attribute__((ext_vector_type(8))) unsigned short;
using f32x4  = __attribute__((ext_vector_type(4))) float;

__device__ __forceinline__ unsigned short f2bf(float f) {
  unsigned int u = __builtin_bit_cast(unsigned int, f);
  u = (u + 0x7FFFu + ((u >> 16) & 1u)) >> 16;   // RNE
  return (unsigned short)u;
}

__device__ __forceinline__ void gl_lds16(const void* g, void* l) {
  __builtin_amdgcn_global_load_lds(
      (const __attribute__((address_space(1))) void*)(g),
      (__attribute__((address_space(3))) void*)(l),
      16, 0, 0);
}

// ---------------------------------------------------------------------------
// K0 (merged): blocks [0,2112): build Bt = [W_cat ; bias ; 0]^T bf16 [HDIM][KP]
//              blocks [2112,2369): WcombT[v][k] + bcomb[v]
__global__ __launch_bounds__(256) void k0_prep(
    const float* __restrict__ W, const float* __restrict__ bias,
    const float* __restrict__ Wsel, const float* __restrict__ bsel,
    unsigned short* __restrict__ Bt, unsigned short* __restrict__ WcombT,
    float* __restrict__ bcomb) {
  __shared__ float wsl[512 * 17];      // padded stride 17: conflict-free
  __shared__ float bm[HDIM];
  __shared__ float part[16][17];
  const int t = threadIdx.x;
  if (blockIdx.x < 2112) {
    int idx = blockIdx.x * 256 + t;    // 1056*512 = 540672 exactly
    int k = idx >> 9;                  // 0..1055
    int n = idx & 511;                 // 0..511
    float val;
    if (k < KDIM)            val = W[(size_t)k * HDIM + n];
    else if (k < KDIM + 16)  val = bias[(size_t)(k - KDIM) * HDIM + n];
    else                     val = 0.f;
    Bt[(size_t)n * KP + k] = f2bf(val);
    return;
  }
  const int bid = blockIdx.x - 2112;   // 0..256
  if (bid < 256) {
    for (int i = t; i < 512 * 16; i += 256) {
      int h = i >> 4, v = i & 15;
      wsl[h * 17 + v] = Wsel[i];
    }
    __syncthreads();
    const int wave = t >> 6, lane = t & 63;
    const int k = bid * 4 + wave;
    const float* wr = W + (size_t)k * HDIM;
    float s[16];
    #pragma unroll
    for (int v = 0; v < 16; ++v) s[v] = 0.f;
    #pragma unroll
    for (int j = 0; j < 8; ++j) {
      const int h = lane + 64 * j;
      const float a = wr[h];
      const float* wl = &wsl[h * 17];
      #pragma unroll
      for (int v = 0; v < 16; ++v) s[v] = fmaf(a, wl[v], s[v]);
    }
    #pragma unroll
    for (int off = 32; off > 0; off >>= 1) {
      #pragma unroll
      for (int v = 0; v < 16; ++v) s[v] += __shfl_xor(s[v], off, 64);
    }
    float mine = 0.f;
    #pragma unroll
    for (int v = 0; v < 16; ++v) mine = (lane == v) ? s[v] : mine;
    if (lane < 16) WcombT[lane * KDIM + k] = f2bf(mine * (1.f / 16.f));
  } else {
    for (int h = t; h < HDIM; h += 256) {
      float s = 0.f;
      #pragma unroll
      for (int v = 0; v < VDIM; ++v) s += bias[v * HDIM + h];
      bm[h] = s * (1.f / 16.f);
    }
    __syncthreads();
    int v = t & 15, sl = t >> 4;
    float s = 0.f;
    for (int h = sl * 32; h < sl * 32 + 32; ++h) s = fmaf(bm[h], Wsel[h * VDIM + v], s);
    part[sl][v] = s;
    __syncthreads();
    if (t < 16) {
      float s2 = bsel[t];
      #pragma unroll
      for (int i = 0; i < 16; ++i) s2 += part[i][t];
      bcomb[t] = s2;
    }
  }
}

// ---------------------------------------------------------------------------
// K1a: partial logits via MFMA, no LDS, no shuffles (unchanged from R2).
// wave = (row-tile rt of 16 rows, K-segment seg of 256). 4096 waves.
__global__ __launch_bounds__(256) void k1a_logits(
    const float* __restrict__ x, const unsigned short* __restrict__ WcombT,
    float* __restrict__ part) {
  const int gw = blockIdx.x * 4 + (threadIdx.x >> 6);
  const int lane = threadIdx.x & 63;
  const int rt = gw >> 2, seg = gw & 3;
  const int m = lane & 15, quad = lane >> 4;
  const float* xr = x + (size_t)(rt * 16 + m) * KDIM + seg * 256 + quad * 8;
  const unsigned short* br = WcombT + m * KDIM + seg * 256 + quad * 8;
  f32x4 acc = {0.f, 0.f, 0.f, 0.f};
  #pragma unroll
  for (int kt = 0; kt < 8; ++kt) {
    float4 a0 = *(const float4*)(xr);
    float4 a1 = *(const float4*)(xr + 4);
    xr += 32;
    u16x8 u;
    u[0] = f2bf(a0.x); u[1] = f2bf(a0.y); u[2] = f2bf(a0.z); u[3] = f2bf(a0.w);
    u[4] = f2bf(a1.x); u[5] = f2bf(a1.y); u[6] = f2bf(a1.z); u[7] = f2bf(a1.w);
    bf16x8 af = __builtin_bit_cast(bf16x8, u);
    bf16x8 bfv = *(const bf16x8*)(br);
    br += 32;
    acc = __builtin_amdgcn_mfma_f32_16x16x32_bf16(af, bfv, acc, 0, 0, 0);
  }
  float* pr = part + (size_t)(rt * 16 + quad * 4) * 64 + seg * 16 + m;
  #pragma unroll
  for (int r = 0; r < 4; ++r) pr[(size_t)r * 64] = acc[r];
}

// ---------------------------------------------------------------------------
// K1b0: thread-per-row softmax -> wts[row][16] fp32 only.
__global__ __launch_bounds__(256) void k1b0_softmax(
    const float* __restrict__ part, const float* __restrict__ bcomb,
    float* __restrict__ weights) {
  const int row = blockIdx.x * 256 + threadIdx.x;
  const float* p = part + (size_t)row * 64;
  float l[16];
  float mx = -1e30f;
  #pragma unroll
  for (int v = 0; v < 16; ++v) {
    l[v] = bcomb[v] + p[v] + p[16 + v] + p[32 + v] + p[48 + v];
    mx = fmaxf(mx, l[v]);
  }
  float s = 0.f;
  #pragma unroll
  for (int v = 0; v < 16; ++v) { l[v] = __expf(l[v] - mx); s += l[v]; }
  const float inv = 1.f / s;
  float4* wout = (float4*)(weights + (size_t)row * 16);
  #pragma unroll
  for (int q = 0; q < 4; ++q) {
    float4 f;
    f.x = l[4 * q + 0] * inv; f.y = l[4 * q + 1] * inv;
    f.z = l[4 * q + 2] * inv; f.w = l[4 * q + 3] * inv;
    wout[q] = f;
  }
}

// ---------------------------------------------------------------------------
// K2f: fused scale+GEMM. C[16384][512] = A' @ Bt^T where
//   A'[b][k]      = wts[b][k>>6] * x[b][k]        (k < 1024, built in staging)
//   A'[b][1024+v] = wts[b][v], A'[b][1040..] = 0  (tail iter)
// Block tile M64 x N128, 4 waves in 2x2 (wave-tile 32x64), BK=32, 33 iters,
// grid 1024 = 4 blocks/CU. A: fp32 global -> scale -> bf16 -> padded LDS
// (stride 40 elems: conflict-free frag reads). B: global_load_lds with XOR
// k-chunk swizzle (4-way residual instead of 8-way).
__global__ __launch_bounds__(256, 4) void k2f_gemm(
    const float* __restrict__ x, const float* __restrict__ wts,
    const unsigned short* __restrict__ Bt, float* __restrict__ C) {
  __shared__ unsigned short As[64 * 40];    // 5120 B, padded
  __shared__ unsigned short Bs[128 * 32];   // 8192 B, k-chunk swizzled

  const int t = threadIdx.x;
  const int wave = t >> 6, lane = t & 63;
  const int tm = blockIdx.x >> 2, tn = blockIdx.x & 3;
  const int mlane = lane & 15, quad = lane >> 4;
  const int wr = wave >> 1, wc = wave & 1;   // wave-tile: rows wr*32, cols wc*64

  // ---- A staging indices (thread-level): 64 rows x 32 k fp32 per iter
  const int arow = t >> 2;                   // 0..63
  const int kq = (t & 3) * 8;                // 0,8,16,24
  const int grow = tm * 64 + arow;
  const float* xrow = x + (size_t)grow * KDIM + kq;       // + kt*32 per iter
  const float* wrow = wts + (size_t)grow * 16;
  unsigned short* asw = &As[arow * 40 + kq];

  // ---- B staging indices (wave-level gl_lds): 8 chunks of 16 n-rows
  const int c0 = wave * 2;
  const int nrow = lane >> 2;                // 0..15 within chunk
  const int ksw = ((lane & 3) ^ (nrow & 3)) * 8;   // XOR swizzle (global side)
  const unsigned short* bg0 = Bt + (size_t)(tn * 128 + (c0 + 0) * 16 + nrow) * KP + ksw;
  const unsigned short* bg1 = Bt + (size_t)(tn * 128 + (c0 + 1) * 16 + nrow) * KP + ksw;
  unsigned short* bsd0 = &Bs[(c0 + 0) * 16 * 32];
  unsigned short* bsd1 = &Bs[(c0 + 1) * 16 * 32];

  // ---- fragment read pointers
  const unsigned short* ap[2];
  #pragma unroll
  for (int i = 0; i < 2; ++i)
    ap[i] = &As[(wr * 32 + i * 16 + mlane) * 40 + quad * 8];
  const unsigned short* bp[4];
  #pragma unroll
  for (int j = 0; j < 4; ++j) {
    const int nl = wc * 64 + j * 16 + mlane;
    bp[j] = &Bs[nl * 32 + ((quad ^ (mlane & 3)) * 8)];   // un-swizzle
  }

  f32x4 acc[2][4];
  const f32x4 z = {0.f, 0.f, 0.f, 0.f};
  #pragma unroll
  for (int i = 0; i < 2; ++i)
    #pragma unroll
    for (int j = 0; j < 4; ++j) acc[i][j] = z;

  for (int kt = 0; kt < 33; ++kt) {
    // B: async DMA into LDS
    gl_lds16(bg0, bsd0);
    gl_lds16(bg1, bsd1);
    bg0 += 32; bg1 += 32;
    // A: fp32 load -> scale by w -> bf16 -> LDS
    float vals[8];
    if (kt < 32) {
      const float4 a0 = *(const float4*)(xrow);
      const float4 a1 = *(const float4*)(xrow + 4);
      xrow += 32;
      const float w = wrow[kt >> 1];         // v = kt>>1, constant per iter
      vals[0] = w * a0.x; vals[1] = w * a0.y; vals[2] = w * a0.z; vals[3] = w * a0.w;
      vals[4] = w * a1.x; vals[5] = w * a1.y; vals[6] = w * a1.z; vals[7] = w * a1.w;
    } else {
      // tail: A'[row][1024+v] = w[v] for v<16, else 0
      if (kq < 16) {
        const float4 w0 = *(const float4*)(wrow + kq);
        const float4 w1 = *(const float4*)(wrow + kq + 4);
        vals[0] = w0.x; vals[1] = w0.y; vals[2] = w0.z; vals[3] = w0.w;
        vals[4] = w1.x; vals[5] = w1.y; vals[6] = w1.z; vals[7] = w1.w;
      } else {
        #pragma unroll
        for (int j = 0; j < 8; ++j) vals[j] = 0.f;
      }
    }
    u16x8 u;
    #pragma unroll
    for (int j = 0; j < 8; ++j) u[j] = f2bf(vals[j]);
    *(u16x8*)asw = u;

    __syncthreads();                         // staging complete
    bf16x8 af[2], bfv[4];
    #pragma unroll
    for (int i = 0; i < 2; ++i) af[i]  = *(const bf16x8*)ap[i];
    #pragma unroll
    for (int j = 0; j < 4; ++j) bfv[j] = *(const bf16x8*)bp[j];
    #pragma unroll
    for (int i = 0; i < 2; ++i)
      #pragma unroll
      for (int j = 0; j < 4; ++j)
        acc[i][j] = __builtin_amdgcn_mfma_f32_16x16x32_bf16(af[i], bfv[j], acc[i][j], 0, 0, 0);
    __syncthreads();                         // readers done before next stage
  }

  // epilogue: C/D layout col=lane&15, row=quad*4+reg  [m89/m91]
  const size_t rowb = (size_t)(tm * 64 + wr * 32);
  const int colb = tn * 128 + wc * 64;
  #pragma unroll
  for (int i = 0; i < 2; ++i)
    #pragma unroll
    for (int j = 0; j < 4; ++j)
      #pragma unroll
      for (int r = 0; r < 4; ++r) {
        const size_t row = rowb + i * 16 + quad * 4 + r;
        const int col = colb + j * 16 + mlane;
        C[row * HDIM + col] = acc[i][j][r];
      }
}

// ---------------------------------------------------------------------------
extern "C" void kernel_launch(void* const* d_in, const int* in_sizes, int n_in,
                              void* d_out, int out_size, void* d_ws, size_t ws_size,
                              hipStream_t stream) {
  const float* x    = (const float*)d_in[0];   // [B, V, S] = [16384][1024] flat
  const float* W    = (const float*)d_in[1];   // [V, S, H] = [1024][512] flat
  const float* bias = (const float*)d_in[2];   // [V, H]
  const float* Wsel = (const float*)d_in[3];   // [H, V]
  const float* bsel = (const float*)d_in[4];   // [V]
  float* out = (float*)d_out;                  // [B, H] fp32

  char* ws = (char*)d_ws;
  unsigned short* Bt     = (unsigned short*)(ws);            // 512*1056*2 = 1,081,344 B
  unsigned short* WcombT = (unsigned short*)(ws + 1081344);  // 16*1024*2  =    32,768 B
  float*          bcomb  = (float*)(ws + 1114112);           // 16*4 (padded to 256)
  float*          part   = (float*)(ws + 1114368);           // 16384*64*4 = 4,194,304 B
  float*          wts    = (float*)(ws + 5308672);           // 16384*16*4 = 1,048,576 B

  k0_prep<<<2369, 256, 0, stream>>>(W, bias, Wsel, bsel, Bt, WcombT, bcomb);
  k1a_logits<<<1024, 256, 0, stream>>>(x, WcombT, part);
  k1b0_softmax<<<64, 256, 0, stream>>>(part, bcomb, wts);
  k2f_gemm<<<1024, 256, 0, stream>>>(x, wts, Bt, out);
}

// Round 4
// 163.540 us; speedup vs baseline: 1.1186x; 1.1186x over previous
//
#include <hip/hip_runtime.h>
#include <hip/hip_bf16.h>
#include <stdint.h>

// Shapes (fixed by the problem)
#define B_ROWS 16384
#define VDIM   16
#define SDIM   64
#define HDIM   512
#define KDIM   1024   // V*S
#define KP     1056   // KDIM + 16 bias cols + 16 zero pad (multiple of 32)
#define ASTR   1064   // LDS A' row stride in elems (1056 + 8 pad: bank-safe)
#define K2_LDS (64 * ASTR * 2)   // 136192 B dynamic LDS

using bf16x8 = __attribute__((ext_vector_type(8))) __bf16;
using u16x8  = __attribute__((ext_vector_type(8))) unsigned short;
using f32x4  = __attribute__((ext_vector_type(4))) float;

__device__ __forceinline__ unsigned short f2bf(float f) {
  unsigned int u = __builtin_bit_cast(unsigned int, f);
  u = (u + 0x7FFFu + ((u >> 16) & 1u)) >> 16;   // RNE
  return (unsigned short)u;
}

// ---------------------------------------------------------------------------
// K0 (merged): blocks [0,2112): build Bt = [W_cat ; bias ; 0]^T bf16 [HDIM][KP]
//              blocks [2112,2369): WcombT[v][k] + bcomb[v]
__global__ __launch_bounds__(256) void k0_prep(
    const float* __restrict__ W, const float* __restrict__ bias,
    const float* __restrict__ Wsel, const float* __restrict__ bsel,
    unsigned short* __restrict__ Bt, unsigned short* __restrict__ WcombT,
    float* __restrict__ bcomb) {
  __shared__ float wsl[512 * 17];      // padded stride 17: conflict-free
  __shared__ float bm[HDIM];
  __shared__ float part[16][17];
  const int t = threadIdx.x;
  if (blockIdx.x < 2112) {
    int idx = blockIdx.x * 256 + t;    // 1056*512 = 540672 exactly
    int k = idx >> 9;                  // 0..1055
    int n = idx & 511;                 // 0..511
    float val;
    if (k < KDIM)            val = W[(size_t)k * HDIM + n];
    else if (k < KDIM + 16)  val = bias[(size_t)(k - KDIM) * HDIM + n];
    else                     val = 0.f;
    Bt[(size_t)n * KP + k] = f2bf(val);
    return;
  }
  const int bid = blockIdx.x - 2112;   // 0..256
  if (bid < 256) {
    for (int i = t; i < 512 * 16; i += 256) {
      int h = i >> 4, v = i & 15;
      wsl[h * 17 + v] = Wsel[i];
    }
    __syncthreads();
    const int wave = t >> 6, lane = t & 63;
    const int k = bid * 4 + wave;
    const float* wr = W + (size_t)k * HDIM;
    float s[16];
    #pragma unroll
    for (int v = 0; v < 16; ++v) s[v] = 0.f;
    #pragma unroll
    for (int j = 0; j < 8; ++j) {
      const int h = lane + 64 * j;
      const float a = wr[h];
      const float* wl = &wsl[h * 17];
      #pragma unroll
      for (int v = 0; v < 16; ++v) s[v] = fmaf(a, wl[v], s[v]);
    }
    #pragma unroll
    for (int off = 32; off > 0; off >>= 1) {
      #pragma unroll
      for (int v = 0; v < 16; ++v) s[v] += __shfl_xor(s[v], off, 64);
    }
    float mine = 0.f;
    #pragma unroll
    for (int v = 0; v < 16; ++v) mine = (lane == v) ? s[v] : mine;
    if (lane < 16) WcombT[lane * KDIM + k] = f2bf(mine * (1.f / 16.f));
  } else {
    for (int h = t; h < HDIM; h += 256) {
      float s = 0.f;
      #pragma unroll
      for (int v = 0; v < VDIM; ++v) s += bias[v * HDIM + h];
      bm[h] = s * (1.f / 16.f);
    }
    __syncthreads();
    int v = t & 15, sl = t >> 4;
    float s = 0.f;
    for (int h = sl * 32; h < sl * 32 + 32; ++h) s = fmaf(bm[h], Wsel[h * VDIM + v], s);
    part[sl][v] = s;
    __syncthreads();
    if (t < 16) {
      float s2 = bsel[t];
      #pragma unroll
      for (int i = 0; i < 16; ++i) s2 += part[i][t];
      bcomb[t] = s2;
    }
  }
}

// ---------------------------------------------------------------------------
// K1a: partial logits via MFMA, no LDS, no shuffles.
// wave = (row-tile rt of 16 rows, K-segment seg of 256). 4096 waves.
__global__ __launch_bounds__(256) void k1a_logits(
    const float* __restrict__ x, const unsigned short* __restrict__ WcombT,
    float* __restrict__ part) {
  const int gw = blockIdx.x * 4 + (threadIdx.x >> 6);
  const int lane = threadIdx.x & 63;
  const int rt = gw >> 2, seg = gw & 3;
  const int m = lane & 15, quad = lane >> 4;
  const float* xr = x + (size_t)(rt * 16 + m) * KDIM + seg * 256 + quad * 8;
  const unsigned short* br = WcombT + m * KDIM + seg * 256 + quad * 8;
  f32x4 acc = {0.f, 0.f, 0.f, 0.f};
  #pragma unroll
  for (int kt = 0; kt < 8; ++kt) {
    float4 a0 = *(const float4*)(xr);
    float4 a1 = *(const float4*)(xr + 4);
    xr += 32;
    u16x8 u;
    u[0] = f2bf(a0.x); u[1] = f2bf(a0.y); u[2] = f2bf(a0.z); u[3] = f2bf(a0.w);
    u[4] = f2bf(a1.x); u[5] = f2bf(a1.y); u[6] = f2bf(a1.z); u[7] = f2bf(a1.w);
    bf16x8 af = __builtin_bit_cast(bf16x8, u);
    bf16x8 bfv = *(const bf16x8*)(br);
    br += 32;
    acc = __builtin_amdgcn_mfma_f32_16x16x32_bf16(af, bfv, acc, 0, 0, 0);
  }
  float* pr = part + (size_t)(rt * 16 + quad * 4) * 64 + seg * 16 + m;
  #pragma unroll
  for (int r = 0; r < 4; ++r) pr[(size_t)r * 64] = acc[r];
}

// ---------------------------------------------------------------------------
// K1b0: thread-per-row softmax -> wts[row][16] fp32 only.
__global__ __launch_bounds__(256) void k1b0_softmax(
    const float* __restrict__ part, const float* __restrict__ bcomb,
    float* __restrict__ weights) {
  const int row = blockIdx.x * 256 + threadIdx.x;
  const float* p = part + (size_t)row * 64;
  float l[16];
  float mx = -1e30f;
  #pragma unroll
  for (int v = 0; v < 16; ++v) {
    l[v] = bcomb[v] + p[v] + p[16 + v] + p[32 + v] + p[48 + v];
    mx = fmaxf(mx, l[v]);
  }
  float s = 0.f;
  #pragma unroll
  for (int v = 0; v < 16; ++v) { l[v] = __expf(l[v] - mx); s += l[v]; }
  const float inv = 1.f / s;
  float4* wout = (float4*)(weights + (size_t)row * 16);
  #pragma unroll
  for (int q = 0; q < 4; ++q) {
    float4 f;
    f.x = l[4 * q + 0] * inv; f.y = l[4 * q + 1] * inv;
    f.z = l[4 * q + 2] * inv; f.w = l[4 * q + 3] * inv;
    wout[q] = f;
  }
}

// ---------------------------------------------------------------------------
// K2f: fused scale+GEMM, block M64 x N512 (FULL width: x read exactly once).
// 8 waves, wave-tile 64x64. A' = bf16(wts[row][k>>6] * x[row][k]) staged once
// into dynamic LDS (row stride 1064: 2-way-only bank aliasing), bias tail
// (w | zeros) at k=1024..1055. ONE barrier; K-loop (33 iters) barrier-free.
// B fragments read directly from Bt via global dwordx4 (L2-resident, 1 MB).
__global__ __launch_bounds__(512, 2) void k2f_gemm(
    const float* __restrict__ x, const float* __restrict__ wts,
    const unsigned short* __restrict__ Bt, float* __restrict__ C) {
  extern __shared__ unsigned short As[];   // [64][ASTR]

  const int t = threadIdx.x;
  const int rowb = blockIdx.x * 64;

  // ---- staging: 8 threads per row; thread covers k = (t&7)*4 + i*32
  {
    const int srow = t >> 3;              // 0..63
    const int sc = (t & 7) * 4;           // 0,4,...,28
    const float* xr = x + (size_t)(rowb + srow) * KDIM + sc;
    const float* wr = wts + (size_t)(rowb + srow) * 16;
    float wv[16];
    #pragma unroll
    for (int q = 0; q < 4; ++q) {
      float4 f = ((const float4*)wr)[q];
      wv[4 * q + 0] = f.x; wv[4 * q + 1] = f.y; wv[4 * q + 2] = f.z; wv[4 * q + 3] = f.w;
    }
    unsigned short* aw = As + srow * ASTR + sc;
    #pragma unroll 4
    for (int i = 0; i < 32; ++i) {
      const float4 a = *(const float4*)(xr + i * 32);
      const float w = wv[i >> 1];         // v = k>>6 = i>>1 (sc < 32)
      unsigned short o[4];
      o[0] = f2bf(w * a.x); o[1] = f2bf(w * a.y);
      o[2] = f2bf(w * a.z); o[3] = f2bf(w * a.w);
      *(uint2*)(aw + i * 32) = *(const uint2*)o;
    }
    // bias tail: A'[row][1024+j] = bf16(w[j]) for j<16 else 0
    if ((t & 7) < 4) {
      const int j8 = (t & 7) * 8;         // 0,8,16,24
      unsigned short o[8];
      #pragma unroll
      for (int jj = 0; jj < 8; ++jj)
        o[jj] = (j8 + jj < 16) ? f2bf(wv[j8 + jj]) : (unsigned short)0;
      *(u16x8*)(As + srow * ASTR + KDIM + j8) = *(const u16x8*)o;
    }
  }
  __syncthreads();   // the ONLY barrier

  // ---- main loop: wave cg covers cols cg*64..+64, all 64 rows
  const int wave = t >> 6, lane = t & 63;
  const int mlane = lane & 15, quad = lane >> 4;
  const int colb = wave * 64;

  const unsigned short* bp[4];
  #pragma unroll
  for (int j = 0; j < 4; ++j)
    bp[j] = Bt + (size_t)(colb + j * 16 + mlane) * KP + quad * 8;
  const unsigned short* ap[4];
  #pragma unroll
  for (int i = 0; i < 4; ++i)
    ap[i] = As + (i * 16 + mlane) * ASTR + quad * 8;

  f32x4 acc[4][4];
  const f32x4 z = {0.f, 0.f, 0.f, 0.f};
  #pragma unroll
  for (int i = 0; i < 4; ++i)
    #pragma unroll
    for (int j = 0; j < 4; ++j) acc[i][j] = z;

  #pragma unroll 1
  for (int kt = 0; kt < 33; ++kt) {
    bf16x8 bv[4], av[4];
    #pragma unroll
    for (int j = 0; j < 4; ++j) { bv[j] = *(const bf16x8*)bp[j]; bp[j] += 32; }
    #pragma unroll
    for (int i = 0; i < 4; ++i) { av[i] = *(const bf16x8*)ap[i]; ap[i] += 32; }
    #pragma unroll
    for (int i = 0; i < 4; ++i)
      #pragma unroll
      for (int j = 0; j < 4; ++j)
        acc[i][j] = __builtin_amdgcn_mfma_f32_16x16x32_bf16(av[i], bv[j], acc[i][j], 0, 0, 0);
  }

  // ---- epilogue: C/D layout col=lane&15, row=quad*4+reg  [m89/m91]
  #pragma unroll
  for (int i = 0; i < 4; ++i)
    #pragma unroll
    for (int j = 0; j < 4; ++j)
      #pragma unroll
      for (int r = 0; r < 4; ++r) {
        const size_t row = (size_t)rowb + i * 16 + quad * 4 + r;
        const int col = colb + j * 16 + mlane;
        C[row * HDIM + col] = acc[i][j][r];
      }
}

// ---------------------------------------------------------------------------
extern "C" void kernel_launch(void* const* d_in, const int* in_sizes, int n_in,
                              void* d_out, int out_size, void* d_ws, size_t ws_size,
                              hipStream_t stream) {
  const float* x    = (const float*)d_in[0];   // [B, V, S] = [16384][1024] flat
  const float* W    = (const float*)d_in[1];   // [V, S, H] = [1024][512] flat
  const float* bias = (const float*)d_in[2];   // [V, H]
  const float* Wsel = (const float*)d_in[3];   // [H, V]
  const float* bsel = (const float*)d_in[4];   // [V]
  float* out = (float*)d_out;                  // [B, H] fp32

  char* ws = (char*)d_ws;
  unsigned short* Bt     = (unsigned short*)(ws);            // 512*1056*2 = 1,081,344 B
  unsigned short* WcombT = (unsigned short*)(ws + 1081344);  // 16*1024*2  =    32,768 B
  float*          bcomb  = (float*)(ws + 1114112);           // 16*4 (padded to 256)
  float*          part   = (float*)(ws + 1114368);           // 16384*64*4 = 4,194,304 B
  float*          wts    = (float*)(ws + 5308672);           // 16384*16*4 = 1,048,576 B

  static int lds_set = 0;
  if (!lds_set) {
    hipFuncSetAttribute((const void*)k2f_gemm,
                        hipFuncAttributeMaxDynamicSharedMemorySize, K2_LDS);
    lds_set = 1;
  }

  k0_prep<<<2369, 256, 0, stream>>>(W, bias, Wsel, bsel, Bt, WcombT, bcomb);
  k1a_logits<<<1024, 256, 0, stream>>>(x, WcombT, part);
  k1b0_softmax<<<64, 256, 0, stream>>>(part, bcomb, wts);
  k2f_gemm<<<256, 512, K2_LDS, stream>>>(x, wts, Bt, out);
}